// Round 14
// baseline (2611.528 us; speedup 1.0000x reference)
//
#include <hip/hip_runtime.h>
#include <math.h>

// NMT seq2seq fwd: E=512, HE=HD=1024, V=32000, B=64, S=48, T=48.
// R14: per-step operand-traffic cut. proj3 emits bf16 (xp, Yp) -> halves the
// scattered gate-stream bytes in both persistent loops; whhC/dc0 slices preloaded
// to LDS in dec (constant over t); s_sleep(1) in barrier polls (16K spinning
// waves were hammering LLC during every sync). R13's named-accumulator fix kept.

#define S_    48
#define B_    64
#define E_    512
#define H_    1024
#define H4_   4096
#define V_    32000
#define T1_   47
#define NROW_ 3008
#define NROWP 3072
#define NTV_  500
#define NBE   128
#define NBD   128

typedef __bf16 bf16x8 __attribute__((ext_vector_type(8)));
typedef float  f32x4  __attribute__((ext_vector_type(4)));
typedef unsigned short ushort_t;
typedef unsigned long long ull_t;

__device__ __forceinline__ float sigm(float x){ return 1.f/(1.f+expf(-x)); }
__device__ __forceinline__ unsigned short f2bs(float f){
  unsigned u=__float_as_uint(f); u+=0x7fffu+((u>>16)&1u); return (unsigned short)(u>>16);
}
__device__ __forceinline__ float b2f(ushort_t u){ return __uint_as_float(((unsigned)u)<<16); }
__device__ __forceinline__ void gload16(const ushort_t* g, ushort_t* l){
  __builtin_amdgcn_global_load_lds((const __attribute__((address_space(1))) void*)g,
                                   (__attribute__((address_space(3))) void*)l,16,0,0);
}

__device__ __forceinline__ void ast32(void* p, unsigned v){
  __hip_atomic_store((unsigned*)p,v,__ATOMIC_RELAXED,__HIP_MEMORY_SCOPE_AGENT);
}
__device__ __forceinline__ void ast64(void* p, ull_t v){
  __hip_atomic_store((ull_t*)p,v,__ATOMIC_RELAXED,__HIP_MEMORY_SCOPE_AGENT);
}

__device__ __forceinline__ void arrive(unsigned* flags, int idx, unsigned ep){
  if(threadIdx.x==0) ast32(&flags[idx*16], ep);
}
__device__ __forceinline__ void wait_flags(unsigned* flags, int n, unsigned ep){
  for(int i=threadIdx.x;i<n;i+=256){
    while(__hip_atomic_load(&flags[i*16],__ATOMIC_RELAXED,__HIP_MEMORY_SCOPE_AGENT)<ep)
      __builtin_amdgcn_s_sleep(1);
  }
  __syncthreads();
}

// ---- staging: 128 rows x 64 cols via global_load_lds, XOR-swizzled granules ----
__device__ __forceinline__ void stage128(const ushort_t* src, int ld, int k0,
                                         ushort_t* lds, int w, int lane){
  const int rA=lane>>3, gA=lane&7;
#pragma unroll
  for(int i=0;i<4;i++){
    int rb=w*32+i*8;
    int row=rb+rA;
    gload16(src+(size_t)row*ld+k0+(((gA)^(row&7))*8), &lds[rb*64]);
  }
}

// ---- named-accumulator MFMA machinery (no arrays cross function boundaries) ----
#define ACC_DECL \
  f32x4 c00={0,0,0,0},c01={0,0,0,0},c02={0,0,0,0},c03={0,0,0,0}, \
        c10={0,0,0,0},c11={0,0,0,0},c12={0,0,0,0},c13={0,0,0,0}, \
        c20={0,0,0,0},c21={0,0,0,0},c22={0,0,0,0},c23={0,0,0,0}, \
        c30={0,0,0,0},c31={0,0,0,0},c32={0,0,0,0},c33={0,0,0,0};

#define MFMA_ __builtin_amdgcn_mfma_f32_16x16x32_bf16
#define MMA_K64(AsB,BsB) do{ \
  _Pragma("unroll") \
  for(int ks_=0;ks_<2;ks_++){ \
    const int sw_=((ks_*4+l4)^l7)*8; \
    bf16x8 a0_=*(const bf16x8*)&(AsB)[(wm*64+ 0+l15)*64+sw_]; \
    bf16x8 a1_=*(const bf16x8*)&(AsB)[(wm*64+16+l15)*64+sw_]; \
    bf16x8 a2_=*(const bf16x8*)&(AsB)[(wm*64+32+l15)*64+sw_]; \
    bf16x8 a3_=*(const bf16x8*)&(AsB)[(wm*64+48+l15)*64+sw_]; \
    bf16x8 b0_=*(const bf16x8*)&(BsB)[(wn*64+ 0+l15)*64+sw_]; \
    bf16x8 b1_=*(const bf16x8*)&(BsB)[(wn*64+16+l15)*64+sw_]; \
    bf16x8 b2_=*(const bf16x8*)&(BsB)[(wn*64+32+l15)*64+sw_]; \
    bf16x8 b3_=*(const bf16x8*)&(BsB)[(wn*64+48+l15)*64+sw_]; \
    c00=MFMA_(a0_,b0_,c00,0,0,0); c01=MFMA_(a0_,b1_,c01,0,0,0); \
    c02=MFMA_(a0_,b2_,c02,0,0,0); c03=MFMA_(a0_,b3_,c03,0,0,0); \
    c10=MFMA_(a1_,b0_,c10,0,0,0); c11=MFMA_(a1_,b1_,c11,0,0,0); \
    c12=MFMA_(a1_,b2_,c12,0,0,0); c13=MFMA_(a1_,b3_,c13,0,0,0); \
    c20=MFMA_(a2_,b0_,c20,0,0,0); c21=MFMA_(a2_,b1_,c21,0,0,0); \
    c22=MFMA_(a2_,b2_,c22,0,0,0); c23=MFMA_(a2_,b3_,c23,0,0,0); \
    c30=MFMA_(a3_,b0_,c30,0,0,0); c31=MFMA_(a3_,b1_,c31,0,0,0); \
    c32=MFMA_(a3_,b2_,c32,0,0,0); c33=MFMA_(a3_,b3_,c33,0,0,0); \
  } \
}while(0)

// ---- proj3: z=0 xprojF, z=1 xprojB, z=2 yproj. BF16 out + optional bias ----
__global__ __launch_bounds__(256)
void proj3(const ushort_t* __restrict__ Xb, const ushort_t* __restrict__ WfB, const float* __restrict__ bf,
           const ushort_t* __restrict__ XrB, const ushort_t* __restrict__ WbB, const float* __restrict__ bb,
           const ushort_t* __restrict__ Yb, const ushort_t* __restrict__ WyB,
           ushort_t* __restrict__ XpF, ushort_t* __restrict__ XpB, ushort_t* __restrict__ Yp)
{
  __shared__ __align__(16) ushort_t As[128*64];
  __shared__ __align__(16) ushort_t Bs[128*64];
  const ushort_t* A; const ushort_t* B; const float* bias; ushort_t* C;
  if(blockIdx.z==0){A=Xb;B=WfB;bias=bf;C=XpF;}
  else if(blockIdx.z==1){A=XrB;B=WbB;bias=bb;C=XpB;}
  else {A=Yb;B=WyB;bias=nullptr;C=Yp;}
  const int tid=threadIdx.x, w=tid>>6, lane=tid&63;
  const int wm=w>>1, wn=w&1;
  const int l15=lane&15, l4=lane>>4, l7=lane&7;
  const int m0=blockIdx.x*128, n0=blockIdx.y*128;
  ACC_DECL
  for(int k0=0;k0<E_;k0+=64){
    stage128(A+(size_t)m0*E_, E_, k0, As, w, lane);
    stage128(B+(size_t)n0*E_, E_, k0, Bs, w, lane);
    __syncthreads();
    MMA_K64(As,Bs);
    __syncthreads();
  }
  const int cr=l4*4, cc=l15;
#define PSTORE(CM,mi,ni) { int col=n0+wn*64+(ni)*16+cc; float bv=bias?bias[col]:0.f; \
  _Pragma("unroll") for(int j=0;j<4;j++){ int row=m0+wm*64+(mi)*16+cr+j; \
    C[(size_t)row*H4_+col]=f2bs(CM[j]+bv); } }
  PSTORE(c00,0,0) PSTORE(c01,0,1) PSTORE(c02,0,2) PSTORE(c03,0,3)
  PSTORE(c10,1,0) PSTORE(c11,1,1) PSTORE(c12,1,2) PSTORE(c13,1,3)
  PSTORE(c20,2,0) PSTORE(c21,2,1) PSTORE(c22,2,2) PSTORE(c23,2,3)
  PSTORE(c30,3,0) PSTORE(c31,3,1) PSTORE(c32,3,2) PSTORE(c33,3,3)
#undef PSTORE
}

// ---- bproj: bf16-out NT GEMM (encP and G) ----
__global__ __launch_bounds__(256)
void bproj(const ushort_t* __restrict__ A, int lda,
           const ushort_t* __restrict__ B, int ldb, int K,
           ushort_t* __restrict__ Cb)
{
  __shared__ __align__(16) ushort_t As[128*64];
  __shared__ __align__(16) ushort_t Bs[128*64];
  const int tid=threadIdx.x, w=tid>>6, lane=tid&63;
  const int wm=w>>1, wn=w&1;
  const int l15=lane&15, l4=lane>>4, l7=lane&7;
  const int m0=blockIdx.x*128, n0=blockIdx.y*128;
  ACC_DECL
  for(int k0=0;k0<K;k0+=64){
    stage128(A+(size_t)m0*lda, lda, k0, As, w, lane);
    stage128(B+(size_t)n0*ldb, ldb, k0, Bs, w, lane);
    __syncthreads();
    MMA_K64(As,Bs);
    __syncthreads();
  }
  const int cr=l4*4, cc=l15;
#define BSTORE(CM,mi,ni) { int col=n0+wn*64+(ni)*16+cc; \
  _Pragma("unroll") for(int j=0;j<4;j++){ int row=m0+wm*64+(mi)*16+cr+j; \
    Cb[(size_t)row*H_+col]=f2bs(CM[j]); } }
  BSTORE(c00,0,0) BSTORE(c01,0,1) BSTORE(c02,0,2) BSTORE(c03,0,3)
  BSTORE(c10,1,0) BSTORE(c11,1,1) BSTORE(c12,1,2) BSTORE(c13,1,3)
  BSTORE(c20,2,0) BSTORE(c21,2,1) BSTORE(c22,2,2) BSTORE(c23,2,3)
  BSTORE(c30,3,0) BSTORE(c31,3,1) BSTORE(c32,3,2) BSTORE(c33,3,3)
#undef BSTORE
}

// ---- vocab GEMM 128x128 + fused LSE partials (tile-major) + gold gather ----
__global__ __launch_bounds__(256)
void mfma_vocab(const ushort_t* __restrict__ A, const ushort_t* __restrict__ B,
                const int* __restrict__ tgt,
                float* __restrict__ pmax, float* __restrict__ psum, float* __restrict__ gold)
{
  __shared__ __align__(16) ushort_t As[128*64];
  __shared__ __align__(16) ushort_t Bs[128*64];
  const int tid=threadIdx.x, w=tid>>6, lane=tid&63;
  const int wm=w>>1, wn=w&1;
  const int l15=lane&15, l4=lane>>4, l7=lane&7;
  const int m0=blockIdx.x*128, n0=blockIdx.y*128;
  ACC_DECL
  for(int k0=0;k0<H_;k0+=64){
    stage128(A+(size_t)m0*H_, H_, k0, As, w, lane);
    stage128(B+(size_t)n0*H_, H_, k0, Bs, w, lane);
    __syncthreads();
    MMA_K64(As,Bs);
    __syncthreads();
  }
  const int tile=blockIdx.y*2+wn;
  const int cc=l15;
#define VEPI(mi,R0,R1,R2,R3) { \
  _Pragma("unroll") for(int j=0;j<4;j++){ \
    int row=m0+wm*64+(mi)*16+l4*4+j; \
    float m=fmaxf(fmaxf(R0[j],R1[j]),fmaxf(R2[j],R3[j])); \
    for(int o=1;o<16;o<<=1) m=fmaxf(m,__shfl_xor(m,o,64)); \
    float s=expf(R0[j]-m)+expf(R1[j]-m)+expf(R2[j]-m)+expf(R3[j]-m); \
    for(int o=1;o<16;o<<=1) s+=__shfl_xor(s,o,64); \
    if(row<NROW_){ \
      if(cc==0){ pmax[(size_t)tile*NROWP+row]=m; psum[(size_t)tile*NROWP+row]=s; } \
      int g=tgt[((row>>6)+1)*B_+(row&63)]; \
      int lj=g-(n0+wn*64); \
      if(lj>=0&&lj<64&&(lj&15)==cc){ int q=lj>>4; \
        gold[row]= (q==0)?R0[j]:(q==1)?R1[j]:(q==2)?R2[j]:R3[j]; } \
    } } }
  VEPI(0,c00,c01,c02,c03)
  VEPI(1,c10,c11,c12,c13)
  VEPI(2,c20,c21,c22,c23)
  VEPI(3,c30,c31,c32,c33)
#undef VEPI
}

// ====== persistent encoder: rotating h slots; bf16 xp; sc1 writes, normal reads =====
__global__ __launch_bounds__(256)
void enc_persist(const ushort_t* __restrict__ WhhB2,
                 const ushort_t* __restrict__ XpF, const ushort_t* __restrict__ XpB,
                 const int* __restrict__ lens,
                 ushort_t* __restrict__ hroll,
                 float* __restrict__ cst,
                 ushort_t* __restrict__ outF, ushort_t* __restrict__ outBR,
                 unsigned* __restrict__ flagsE)
{
  __shared__ __align__(16) ushort_t Bp[64*1024];
  const int tid=threadIdx.x, w=tid>>6, lane=tid&63;
  const int blk=blockIdx.x, dir=blk>>6, j0=(blk&63)*16;
  const int l15=lane&15, l4=lane>>4;
  const ushort_t* Wd=WhhB2+(size_t)dir*H4_*H_;
  const ushort_t* xp = dir? XpB : XpF;
  float* cD = cst + (size_t)dir*65536;
  ushort_t* outD = dir? outBR : outF;
  unsigned* fD = flagsE + dir*64*16;

  for(int p=0;p<32;p++){
    int s=p*256+w*64+lane;
    int row=s>>7, g=s&127;
    int grow=((row>>4)<<10)+j0+(row&15);
    gload16(Wd+(size_t)grow*H_+((g^(row&7))*8), &Bp[(p*256+w*64)*8]);
  }
  __syncthreads();

  float hkeep[4]={0.f,0.f,0.f,0.f};

  for(int t=0;t<S_;t++){
    const ushort_t* hbR = hroll + ((size_t)t*2+dir)*65536;
    ushort_t*       hbW = hroll + ((size_t)(t+1)*2+dir)*65536;
    bf16x8 a[32];
    {
      const ushort_t* ap=hbR+(size_t)(w*16+l15)*H_+l4*8;
#pragma unroll
      for(int kk=0;kk<32;kk++) a[kk]=*(const bf16x8*)(ap+kk*32);
    }
    f32x4 acc[4];
#pragma unroll
    for(int n=0;n<4;n++) acc[n]=(f32x4){0.f,0.f,0.f,0.f};
#pragma unroll
    for(int kk=0;kk<32;kk++){
#pragma unroll
      for(int n=0;n<4;n++){
        int rb=n*16+l15;
        bf16x8 b=*(const bf16x8*)&Bp[rb*H_+(((kk*4+l4)^(rb&7))*8)];
        acc[n]=__builtin_amdgcn_mfma_f32_16x16x32_bf16(a[kk],b,acc[n],0,0,0);
      }
    }
    const int col=j0+l15;
#pragma unroll
    for(int j=0;j<4;j++){
      int row=w*16+l4*4+j;
      const ushort_t* xr=xp+(size_t)(t*64+row)*H4_;
      float g0=acc[0][j]+b2f(xr[col]);
      float g1=acc[1][j]+b2f(xr[1024+col]);
      float g2=acc[2][j]+b2f(xr[2048+col]);
      float g3=acc[3][j]+b2f(xr[3072+col]);
      size_t ix=(size_t)row*H_+col;
      float c_old=cD[ix];
      float cn=sigm(g1)*c_old+sigm(g0)*tanhf(g2);
      float hv=sigm(g3)*tanhf(cn);
      bool m=t<lens[row];
      cD[ix]= m? cn : c_old;
      hkeep[j]= m? hv : hkeep[j];
      outD[(size_t)(t*64+row)*H_+col]= m? f2bs(hv) : (ushort_t)0;
      ushort_t h16=f2bs(hkeep[j]);
      ushort_t other=(ushort_t)__shfl_xor((int)h16,1,64);
      if((lane&1)==0)
        ast32((void*)(hbW+ix), (unsigned)h16 | ((unsigned)other<<16));
    }
    __syncthreads();
    arrive(fD, blk&63, (unsigned)(t+1));
    wait_flags(fD, 64, (unsigned)(t+1));
  }
}

// ====== persistent decoder: bf16 Yp; whhC/dc0 LDS-resident; rotating slots ==========
__global__ __launch_bounds__(256)
void dec_persist(const ushort_t* __restrict__ WoB,
                 const ushort_t* __restrict__ Yp,     // bf16 [3072][4096]
                 const float* __restrict__ whhC,
                 const float* __restrict__ dc0,
                 const ushort_t* __restrict__ encPb,
                 const ushort_t* __restrict__ Gb,
                 const ushort_t* __restrict__ WcombB,
                 const int* __restrict__ lens,
                 ushort_t* __restrict__ opRoll,
                 ushort_t* __restrict__ hRoll,
                 ushort_t* __restrict__ aGRoll,
                 ushort_t* __restrict__ combB,
                 unsigned* __restrict__ fA,
                 unsigned* __restrict__ fB,
                 unsigned* __restrict__ fC)
{
  __shared__ __align__(16) ushort_t Bp[32*1024];
  __shared__ __align__(16) ushort_t WcHp[16*1024];
  __shared__ float gbuf[64*32];
  __shared__ float whhCs[64*32];    // [row][gate*8+c], cols j0..j0+7
  __shared__ float dc0s[64*8];
  __shared__ float es[S_], al[S_];
  const int tid=threadIdx.x, w=tid>>6, lane=tid&63;
  const int blk=blockIdx.x;
  const int l15=lane&15, l4=lane>>4;
  const int j0=blk*8;
  const int b=blk;
  const int j0c=(blk-64)*16;

  for(int p=0;p<16;p++){
    int s=p*256+w*64+lane;
    int row=s>>7, g=s&127;
    int grow=((row>>3)<<10)+j0+(row&7);
    gload16(WoB+(size_t)grow*H_+((g^(row&7))*8), &Bp[(p*256+w*64)*8]);
  }
  if(blk>=64){
    for(int p=0;p<8;p++){
      int s=p*256+w*64+lane;
      int row=s>>7, g=s&127;
      gload16(WcombB+(size_t)(j0c+row)*3072+2048+((g^(row&7))*8), &WcHp[(p*256+w*64)*8]);
    }
  }
  // whhC/dc0 slices (constant over t) -> LDS
  for(int p=0;p<8;p++){
    int s=p*256+tid;            // s = row*32 + gate*8 + c
    int row=s>>5, gc=s&31, gate=gc>>3, c=gc&7;
    whhCs[s]=whhC[(size_t)row*H4_+gate*1024+j0+c];
  }
  if(tid<512){ int row=tid>>3, c=tid&7; dc0s[tid]=dc0[(size_t)row*H_+j0+c]; }
  __syncthreads();

  f32x4 accP=(f32x4){0.f,0.f,0.f,0.f};
  for(int t=0;t<T1_;t++){
    const unsigned ept=(unsigned)(t+1);
    const ushort_t* opT = opRoll + (size_t)t*65536;
    ushort_t*       opW = opRoll + (size_t)(t+1)*65536;
    ushort_t*       hT  = hRoll  + (size_t)t*65536;
    ushort_t*       aGT = aGRoll + (size_t)t*65536;
    // ---------------- PA ----------------
    {
      bf16x8 a[32];
      {
        const ushort_t* ap=opT+(size_t)(w*16+l15)*H_+l4*8;
#pragma unroll
        for(int kk=0;kk<32;kk++) a[kk]=*(const bf16x8*)(ap+kk*32);
      }
      f32x4 acc0=(f32x4){0.f,0.f,0.f,0.f}, acc1=(f32x4){0.f,0.f,0.f,0.f};
#pragma unroll
      for(int kk=0;kk<32;kk++){
        int rb0=l15, rb1=16+l15;
        bf16x8 b0=*(const bf16x8*)&Bp[rb0*1024+(((kk*4+l4)^(rb0&7))*8)];
        bf16x8 b1=*(const bf16x8*)&Bp[rb1*1024+(((kk*4+l4)^(rb1&7))*8)];
        acc0=__builtin_amdgcn_mfma_f32_16x16x32_bf16(a[kk],b0,acc0,0,0,0);
        acc1=__builtin_amdgcn_mfma_f32_16x16x32_bf16(a[kk],b1,acc1,0,0,0);
      }
#pragma unroll
      for(int j=0;j<4;j++){
        gbuf[(w*16+l4*4+j)*32 + l15   ]=acc0[j];
        gbuf[(w*16+l4*4+j)*32 + 16+l15]=acc1[j];
      }
      __syncthreads();
      {
        int o=tid*2, row=o>>3, c=o&7;
        const ushort_t* ypr=Yp+(size_t)(t*64+row)*H4_;
        float hv2[2];
#pragma unroll
        for(int q=0;q<2;q++){
          int cc=c+q;
          float g0=gbuf[row*32+cc]   +b2f(ypr[j0+cc])     +whhCs[row*32+cc];
          float g1=gbuf[row*32+8+cc] +b2f(ypr[1024+j0+cc])+whhCs[row*32+8+cc];
          float g2=gbuf[row*32+16+cc]+b2f(ypr[2048+j0+cc])+whhCs[row*32+16+cc];
          float g3=gbuf[row*32+24+cc]+b2f(ypr[3072+j0+cc])+whhCs[row*32+24+cc];
          float cn=sigm(g1)*dc0s[row*8+cc]+sigm(g0)*tanhf(g2);
          hv2[q]=sigm(g3)*tanhf(cn);
        }
        unsigned pk=(unsigned)f2bs(hv2[0]) | ((unsigned)f2bs(hv2[1])<<16);
        ast32((void*)(hT+(size_t)row*H_+j0+c), pk);
      }
    }
    __syncthreads();
    arrive(fA, blk, ept);
    wait_flags(fA, 128, ept);

    if(blk<64){
      // ------------- PB ----------------
      float hreg[16];
      {
        const ushort_t* hp=hT+(size_t)b*H_+lane*16;
        bf16x8 h0=*(const bf16x8*)hp, h1=*(const bf16x8*)(hp+8);
#pragma unroll
        for(int i=0;i<8;i++){ hreg[i]=b2f(((const ushort_t*)&h0)[i]);
                              hreg[8+i]=b2f(((const ushort_t*)&h1)[i]); }
      }
      for(int s=w;s<S_;s+=4){
        const ushort_t* epr=encPb+((size_t)b*S_+s)*H_+lane*16;
        bf16x8 e0=*(const bf16x8*)epr, e1=*(const bf16x8*)(epr+8);
        float sum=0.f;
#pragma unroll
        for(int i=0;i<8;i++) sum+=b2f(((const ushort_t*)&e0)[i])*hreg[i]
                                +b2f(((const ushort_t*)&e1)[i])*hreg[8+i];
        for(int o=32;o>0;o>>=1) sum+=__shfl_xor(sum,o,64);
        if(lane==0) es[s]=sum;
      }
      __syncthreads();
      if(tid<64){
        int L=lens[b];
        float e=(tid<S_&&tid<L)? es[tid] : -INFINITY;
        float m=e;
        for(int o=32;o>0;o>>=1) m=fmaxf(m,__shfl_xor(m,o,64));
        float p=(tid<S_)? expf(e-m):0.f;
        float sm=p;
        for(int o=32;o>0;o>>=1) sm+=__shfl_xor(sm,o,64);
        if(tid<S_) al[tid]=p/sm;
      }
      __syncthreads();
      {
        float r0=0.f,r1=0.f,r2=0.f,r3=0.f;
        const int c4=tid*4;
        for(int s=0;s<S_;s++){
          float aa=al[s];
          ushort4 g4=*(const ushort4*)(Gb+((size_t)b*S_+s)*H_+c4);
          r0+=aa*b2f(g4.x); r1+=aa*b2f(g4.y); r2+=aa*b2f(g4.z); r3+=aa*b2f(g4.w);
        }
        ull_t pk=(ull_t)f2bs(r0) | ((ull_t)f2bs(r1)<<16)
               | ((ull_t)f2bs(r2)<<32) | ((ull_t)f2bs(r3)<<48);
        ast64((void*)(aGT+(size_t)b*H_+c4), pk);
      }
      __syncthreads();
      arrive(fB, blk, ept);
      wait_flags(fC, 64, ept);
    } else {
      // ------------- PCmm --------------
      bf16x8 a[32];
      {
        const ushort_t* ap=hT+(size_t)(w*16+l15)*H_+l4*8;
#pragma unroll
        for(int kk=0;kk<32;kk++) a[kk]=*(const bf16x8*)(ap+kk*32);
      }
      accP=(f32x4){0.f,0.f,0.f,0.f};
#pragma unroll
      for(int kk=0;kk<32;kk++){
        bf16x8 bb=*(const bf16x8*)&WcHp[l15*1024+(((kk*4+l4)^(l15&7))*8)];
        accP=__builtin_amdgcn_mfma_f32_16x16x32_bf16(a[kk],bb,accP,0,0,0);
      }
      wait_flags(fB, 64, ept);
      // ------------- PCfin -------------
#pragma unroll
      for(int j=0;j<4;j++){
        int row=w*16+l4*4+j, col=j0c+l15;
        float av=b2f(aGT[(size_t)row*H_+col]);
        float o=tanhf(accP[j]+av);
        ushort_t ob=f2bs(o);
        combB[((size_t)t*64+row)*H_+col]=ob;
        ushort_t other=(ushort_t)__shfl_xor((int)ob,1,64);
        if((lane&1)==0)
          ast32((void*)(opW+(size_t)row*H_+col), (unsigned)ob | ((unsigned)other<<16));
      }
      __syncthreads();
      arrive(fC, blk-64, ept);
      wait_flags(fC, 64, ept);
    }
  }
}

// ------------------ embeddings (direct to bf16): X, Xrev, Y -------------------------
__global__ void embed_all(const int* __restrict__ src, const int* __restrict__ tgt,
                          const int* __restrict__ lens,
                          const float* __restrict__ se, const float* __restrict__ te,
                          ushort_t* __restrict__ X, ushort_t* __restrict__ Xr,
                          ushort_t* __restrict__ Y)
{
  int bi=blockIdx.x, tid=threadIdx.x;
  const float* srcrow; ushort_t* dst;
  if(bi<3072){
    int s=bi>>6, b=bi&63;
    srcrow=se+(size_t)src[s*64+b]*E_; dst=X+(size_t)bi*E_;
  } else if(bi<6144){
    int r=bi-3072, t=r>>6, b=r&63;
    int L=lens[b]; int ts=(t<L)? L-1-t : t;
    srcrow=se+(size_t)src[ts*64+b]*E_; dst=Xr+(size_t)r*E_;
  } else {
    int r=bi-6144, t=r>>6, b=r&63;
    srcrow=te+(size_t)tgt[t*64+b]*E_; dst=Y+(size_t)r*E_;
  }
  float4 v=((const float4*)srcrow)[tid];
  ushort4 o; o.x=f2bs(v.x); o.y=f2bs(v.y); o.z=f2bs(v.z); o.w=f2bs(v.w);
  ((ushort4*)dst)[tid]=o;
}

// ------------- weight conversions fp32->bf16 (all but W_voc), grid-stride -----------
__global__ void prep_w(const float* __restrict__ Whhf,const float* __restrict__ Whhb,
                       const float* __restrict__ Wihf,const float* __restrict__ Wihb,
                       const float* __restrict__ Watt,const float* __restrict__ dWih,
                       const float* __restrict__ Wcomb,
                       ushort_t* __restrict__ WhhfB,ushort_t* __restrict__ WhhbB,
                       ushort_t* __restrict__ WihfB,ushort_t* __restrict__ WihbB,
                       ushort_t* __restrict__ WattB,ushort_t* __restrict__ dWihYb,
                       ushort_t* __restrict__ dWihOb,ushort_t* __restrict__ WcombB)
{
  const int NQ=6029312;
  for(int q=blockIdx.x*256+threadIdx.x; q<NQ; q+=gridDim.x*256){
    const float* src; ushort_t* dst; size_t si,di; int r;
    if(q<1048576){ si=(size_t)q*4; src=Whhf; dst=WhhfB; di=si; }
    else if(q<2097152){ r=q-1048576; si=(size_t)r*4; src=Whhb; dst=WhhbB; di=si; }
    else if(q<2621440){ r=q-2097152; si=(size_t)r*4; src=Wihf; dst=WihfB; di=si; }
    else if(q<3145728){ r=q-2621440; si=(size_t)r*4; src=Wihb; dst=WihbB; di=si; }
    else if(q<3670016){ r=q-3145728; si=(size_t)r*4; src=Watt; dst=WattB; di=si; }
    else if(q<4194304){ r=q-3670016; int row=r>>7, c4=(r&127)*4;
                        si=(size_t)row*1536+c4; src=dWih; dst=dWihYb; di=(size_t)row*512+c4; }
    else if(q<5242880){ r=q-4194304; int row=r>>8, c4=(r&255)*4;
                        si=(size_t)row*1536+512+c4; src=dWih; dst=dWihOb; di=(size_t)row*1024+c4; }
    else { r=q-5242880; si=(size_t)r*4; src=Wcomb; dst=WcombB; di=si; }
    float4 v=*(const float4*)(src+si);
    ushort4 o; o.x=f2bs(v.x);o.y=f2bs(v.y);o.z=f2bs(v.z);o.w=f2bs(v.w);
    *(ushort4*)(dst+di)=o;
  }
}

__global__ void f2b_voc(const float* __restrict__ in, ushort_t* __restrict__ out){
  for(size_t q=blockIdx.x*256+threadIdx.x; q<8192000; q+=(size_t)gridDim.x*256){
    float4 v=*(const float4*)(in+q*4);
    ushort4 o; o.x=f2bs(v.x);o.y=f2bs(v.y);o.z=f2bs(v.z);o.w=f2bs(v.w);
    *(ushort4*)(out+q*4)=o;
  }
}

// --- build enc_hiddens bf16 with bwd un-reversal; concat final h/c (fp32) -----------
__global__ void gather_concat(const ushort_t* __restrict__ outF, const ushort_t* __restrict__ outBR,
                              const int* __restrict__ lens,
                              const ushort_t* __restrict__ hb, const float* __restrict__ cst,
                              ushort_t* __restrict__ encHb,
                              float* __restrict__ hcat, float* __restrict__ ccat)
{
  int bi=blockIdx.x, tid=threadIdx.x;
  if(bi<3072){
    int b=bi/48, s=bi%48;
    int L=lens[b]; int sr=(s<L)? L-1-s : s;
    ((ushort4*)(encHb+(size_t)bi*2048))[tid]      =((const ushort4*)(outF +(size_t)(s*64+b)*H_))[tid];
    ((ushort4*)(encHb+(size_t)bi*2048+1024))[tid] =((const ushort4*)(outBR+(size_t)(sr*64+b)*H_))[tid];
  } else {
    int b=bi-3072;
    for(int i=tid;i<H_;i+=256){
      hcat[(size_t)b*2048+i]      = b2f(hb[(size_t)b*H_+i]);
      hcat[(size_t)b*2048+1024+i] = b2f(hb[65536+(size_t)b*H_+i]);
      ccat[(size_t)b*2048+i]      = cst[(size_t)b*H_+i];
      ccat[(size_t)b*2048+1024+i] = cst[65536+(size_t)b*H_+i];
    }
  }
}

// ---------------- fp32 NT GEMM (small: dh0/dc0/whhC) --------------------------------
template<int BM,int BN,int TM,int TN>
__global__ __launch_bounds__(256)
void gemm_nt(int M, int K,
             const float* __restrict__ A, int lda,
             const float* __restrict__ B, int ldb,
             float* __restrict__ C, int ldc,
             const float* __restrict__ bias)
{
  constexpr int BK=16;
  __shared__ float As[BK][BM+4];
  __shared__ float Bs[BK][BN+4];
  const int tid=threadIdx.x;
  constexpr int TX=BN/TN;
  const int tx=tid%TX, ty=tid/TX;
  const int m0=blockIdx.x*BM, n0=blockIdx.y*BN;
  float acc[TM][TN];
#pragma unroll
  for(int i=0;i<TM;i++)
#pragma unroll
    for(int j=0;j<TN;j++) acc[i][j]=0.f;
  for(int k0=0;k0<K;k0+=BK){
    for(int i=tid;i<BM*4;i+=256){
      int r=i>>2, c=(i&3)*4;
      float4 v=make_float4(0.f,0.f,0.f,0.f);
      if(m0+r<M) v=*(const float4*)(A+(size_t)(m0+r)*lda+k0+c);
      As[c+0][r]=v.x; As[c+1][r]=v.y; As[c+2][r]=v.z; As[c+3][r]=v.w;
    }
    for(int i=tid;i<BN*4;i+=256){
      int r=i>>2, c=(i&3)*4;
      float4 v=*(const float4*)(B+(size_t)(n0+r)*ldb+k0+c);
      Bs[c+0][r]=v.x; Bs[c+1][r]=v.y; Bs[c+2][r]=v.z; Bs[c+3][r]=v.w;
    }
    __syncthreads();
#pragma unroll
    for(int k=0;k<BK;k++){
      float a[TM], bb[TN];
#pragma unroll
      for(int i=0;i<TM;i++) a[i]=As[k][ty*TM+i];
#pragma unroll
      for(int j=0;j<TN;j++) bb[j]=Bs[k][tx*TN+j];
#pragma unroll
      for(int i=0;i<TM;i++)
#pragma unroll
        for(int j=0;j<TN;j++) acc[i][j]+=a[i]*bb[j];
    }
    __syncthreads();
  }
#pragma unroll
  for(int i=0;i<TM;i++){
    int r=m0+ty*TM+i;
    if(r>=M) continue;
#pragma unroll
    for(int j=0;j<TN;j++){
      int c=n0+tx*TN+j;
      float v=acc[i][j];
      if(bias) v+=bias[c];
      C[(size_t)r*ldc+c]=v;
    }
  }
}

// ---- streaming LSE merge over tile-major partials (coalesced, single pass) ---------
__global__ __launch_bounds__(256)
void lse_final(const float* __restrict__ pmax, const float* __restrict__ psum,
               const float* __restrict__ gold, float* __restrict__ gl)
{
  int r=blockIdx.x*256+threadIdx.x;
  if(r>=NROW_) return;
  float M=-INFINITY, S=0.f;
  for(int i=0;i<NTV_;i++){
    float m2=pmax[(size_t)i*NROWP+r];
    float s2=psum[(size_t)i*NROWP+r];
    float Mn=fmaxf(M,m2);
    S = S*expf(M-Mn) + s2*expf(m2-Mn);
    M=Mn;
  }
  gl[r]=gold[r]-(M+logf(S));
}

__global__ void final_sum(const float* __restrict__ gl, const int* __restrict__ tgt,
                          float* __restrict__ out)
{
  int b=threadIdx.x;
  float acc=0.f;
  for(int t=0;t<T1_;t++){
    int tk=tgt[(t+1)*B_+b];
    if(tk!=0) acc+=gl[t*B_+b];
  }
  out[b]=acc;
}

// =====================================================================================
extern "C" void kernel_launch(void* const* d_in, const int* in_sizes, int n_in,
                              void* d_out, int out_size, void* d_ws, size_t ws_size,
                              hipStream_t stream)
{
  (void)in_sizes; (void)n_in; (void)out_size; (void)ws_size;
  const int*   src    =(const int*)  d_in[0];
  const int*   tgt    =(const int*)  d_in[1];
  const int*   lens   =(const int*)  d_in[2];
  const float* src_emb=(const float*)d_in[3];
  const float* tgt_emb=(const float*)d_in[4];
  const float* Wih_f  =(const float*)d_in[5];
  const float* Whh_f  =(const float*)d_in[6];
  const float* b_f    =(const float*)d_in[7];
  const float* Wih_b  =(const float*)d_in[8];
  const float* Whh_b  =(const float*)d_in[9];
  const float* b_b    =(const float*)d_in[10];
  const float* dWih   =(const float*)d_in[11];
  const float* dWhh   =(const float*)d_in[12];
  const float* db     =(const float*)d_in[13];
  const float* W_h    =(const float*)d_in[14];
  const float* W_c    =(const float*)d_in[15];
  const float* W_att  =(const float*)d_in[16];
  const float* W_comb =(const float*)d_in[17];
  const float* W_voc  =(const float*)d_in[18];
  float* out=(float*)d_out;
  float* W  =(float*)d_ws;

  size_t off=0;
  auto AL=[&](size_t n){ size_t o=off; off+=n; return o; };
  // ---- fp32 region (XpF/XpB/Yp regions keep full fp32-era sizes; bf16 data uses
  //      the first half of each -> post-encoder aliases unchanged) ----
  const size_t oXpF  =AL((size_t)3072*H4_);
  const size_t oXpB  =AL((size_t)3072*H4_);
  const size_t oYp   =AL((size_t)3072*H4_);
  const size_t oCst  =AL((size_t)2*64*H_);
  const size_t oHcat =AL((size_t)64*2048);
  const size_t oCcat =AL((size_t)64*2048);
  const size_t oDh0  =AL((size_t)64*H_);
  const size_t oDc0  =AL((size_t)64*H_);
  const size_t oWhhC =AL((size_t)64*H4_);
  const size_t oBar  =AL((size_t)8192);
  // ---- bf16 region ----
  const size_t oXb    =AL((size_t)3072*E_/2);
  const size_t oXrb   =AL((size_t)3072*E_/2);
  const size_t oYb    =AL((size_t)3072*E_/2);
  const size_t oWhhfB =AL((size_t)H4_*H_/2);
  const size_t oWhhbB =AL((size_t)H4_*H_/2);
  const size_t oWihfB =AL((size_t)H4_*E_/2);
  const size_t oWihbB =AL((size_t)H4_*E_/2);
  const size_t oWattB =AL((size_t)H_*2048/2);
  const size_t odWihYb=AL((size_t)H4_*E_/2);
  const size_t odWihOb=AL((size_t)H4_*H_/2);
  const size_t oWcombB=AL((size_t)H_*3072/2);
  const size_t oOutF  =AL((size_t)S_*64*H_/2);
  const size_t oOutBR =AL((size_t)S_*64*H_/2);
  const size_t oEncHb =AL((size_t)3072*2048/2);
  const size_t oEncPb =AL((size_t)3072*H_/2);

  ushort_t* Xb    =(ushort_t*)(W+oXb);
  ushort_t* Xrb   =(ushort_t*)(W+oXrb);
  ushort_t* Yb    =(ushort_t*)(W+oYb);
  ushort_t* WhhfB =(ushort_t*)(W+oWhhfB);
  ushort_t* WihfB =(ushort_t*)(W+oWihfB);
  ushort_t* WihbB =(ushort_t*)(W+oWihbB);
  ushort_t* WattB =(ushort_t*)(W+oWattB);
  ushort_t* dWihYb=(ushort_t*)(W+odWihYb);
  ushort_t* dWihOb=(ushort_t*)(W+odWihOb);
  ushort_t* WcombB=(ushort_t*)(W+oWcombB);
  ushort_t* OutF  =(ushort_t*)(W+oOutF);
  ushort_t* OutBR =(ushort_t*)(W+oOutBR);
  ushort_t* EncHb =(ushort_t*)(W+oEncHb);
  ushort_t* EncPb =(ushort_t*)(W+oEncPb);
  // bf16 views of the proj output regions (first half of each fp32-era region)
  ushort_t* XpFb  =(ushort_t*)(W+oXpF);
  ushort_t* XpBb  =(ushort_t*)(W+oXpB);
  ushort_t* YpB   =(ushort_t*)(W+oYp);
  // ---- aliases in dead XpF+XpB region (post-encoder only; XpFb occupies first
  //      6.29M floats of oXpF, XpBb first 6.29M of oXpB -- both dead by then) ----
  ushort_t* WvocB =(ushort_t*)(W+oXpF);
  float* pmax = W+oXpF+16450000;
  float* psum = pmax + (size_t)NTV_*NROWP;
  ushort_t* Gbuf  =(ushort_t*)(W+oXpF+19550000);
  ushort_t* OpRoll=(ushort_t*)(W+oXpF+21150000);
  ushort_t* HRoll =(ushort_t*)(W+oXpF+22750000);
  float* gold = W+oXpF+24400000;
  float* gl   = gold + NROWP;
  ushort_t* AGRoll=OutBR;
  ushort_t* HrollE=EncHb;
  ushort_t* HbFin =HrollE+(size_t)S_*2*65536;
  ushort_t* CombB =(ushort_t*)(W+oOutF);
  unsigned* flagsE=(unsigned*)(W+oBar);
  unsigned* fA = flagsE + 2*64*16;
  unsigned* fB = fA + 128*16;
  unsigned* fC = fB + 64*16;

  // ---- per-call init ----
  hipMemsetAsync(W+oBar, 0, 8192*sizeof(float), stream);
  hipMemsetAsync(W+oCst, 0, (size_t)2*64*H_*sizeof(float), stream);
  hipMemsetAsync(HrollE, 0, (size_t)2*65536*sizeof(ushort_t), stream);

  // ---- prep ----
  embed_all<<<dim3(3072+3072+NROW_),128,0,stream>>>(src,tgt,lens,src_emb,tgt_emb,Xb,Xrb,Yb);
  prep_w<<<dim3(2048),256,0,stream>>>(Whh_f,Whh_b,Wih_f,Wih_b,W_att,dWih,W_comb,
                                      WhhfB,(ushort_t*)(W+oWhhbB),WihfB,WihbB,WattB,
                                      dWihYb,dWihOb,WcombB);
  proj3<<<dim3(24,32,3),256,0,stream>>>(Xb,WihfB,b_f, Xrb,WihbB,b_b, Yb,dWihYb,
                                        XpFb,XpBb,YpB);

  // ---- encoder ----
  enc_persist<<<dim3(NBE),256,0,stream>>>(WhhfB, XpFb, XpBb, lens,
                                          HrollE, W+oCst, OutF, OutBR, flagsE);

  // OpRoll slot 0 sits in the (now dead) XpB region -> zero after encoder.
  hipMemsetAsync(OpRoll, 0, (size_t)65536*sizeof(ushort_t), stream);

  // ---- mid section ----
  gather_concat<<<dim3(3136),256,0,stream>>>(OutF,OutBR,lens,HbFin,W+oCst,
                                             EncHb,W+oHcat,W+oCcat);
  f2b_voc<<<dim3(2048),256,0,stream>>>(W_voc, WvocB);
  bproj<<<dim3(24,8),256,0,stream>>>(EncHb,2048, WattB,2048, 2048, EncPb);
  bproj<<<dim3(24,8),256,0,stream>>>(EncHb,2048, WcombB,3072, 2048, Gbuf);
  gemm_nt<64,64,4,4><<<dim3(1,16),256,0,stream>>>(64,2048, W+oHcat,2048, W_h,2048, W+oDh0,H_, nullptr);
  gemm_nt<64,64,4,4><<<dim3(1,16),256,0,stream>>>(64,2048, W+oCcat,2048, W_c,2048, W+oDc0,H_, nullptr);
  gemm_nt<64,64,4,4><<<dim3(1,64),256,0,stream>>>(64,H_, W+oDh0,H_, dWhh,H_, W+oWhhC,H4_, db);

  // ---- decoder ----
  dec_persist<<<dim3(NBD),256,0,stream>>>(dWihOb, YpB, W+oWhhC, W+oDc0,
                                          EncPb, Gbuf, WcombB, lens,
                                          OpRoll, HRoll, AGRoll, CombB, fA, fB, fC);

  // ---- vocab + LSE + output ----
  mfma_vocab<<<dim3(24,250),256,0,stream>>>(CombB, WvocB, tgt, pmax, psum, gold);
  lse_final<<<dim3((NROW_+255)/256),256,0,stream>>>(pmax, psum, gold, gl);
  final_sum<<<dim3(1),64,0,stream>>>(gl, tgt, out);
}

// Round 16
// 2213.681 us; speedup vs baseline: 1.1797x; 1.1797x over previous
//
#include <hip/hip_runtime.h>
#include <math.h>

// NMT seq2seq fwd: E=512, HE=HD=1024, V=32000, B=64, S=48, T=48.
// R16 = R15 with two fixes. R15's absmax-14/488 failure: (1) stage256 handed a
// DIVERGENT LDS pointer to global_load_lds (dest must be wave-uniform base +
// lane*16; R11's passing version used the uniform base) -> corrupted vocab tiles;
// (2) accP was rounded to bf16 before tanh(accP+aG). Fixes: uniform-base stage256;
// fp32 accRoll in the dead upper half of the Yp region. Decoder keeps the 2-round
// structure (PCmm -> fM early; PB holds aG in regs, does epilogue, signals fB).

#define S_    48
#define B_    64
#define E_    512
#define H_    1024
#define H4_   4096
#define V_    32000
#define T1_   47
#define NROW_ 3008
#define NROWP 3072
#define NTV_  500
#define NBE   128
#define NBD   128

typedef __bf16 bf16x8 __attribute__((ext_vector_type(8)));
typedef float  f32x4  __attribute__((ext_vector_type(4)));
typedef unsigned short ushort_t;
typedef unsigned long long ull_t;

__device__ __forceinline__ float sigm(float x){ return 1.f/(1.f+expf(-x)); }
__device__ __forceinline__ unsigned short f2bs(float f){
  unsigned u=__float_as_uint(f); u+=0x7fffu+((u>>16)&1u); return (unsigned short)(u>>16);
}
__device__ __forceinline__ float b2f(ushort_t u){ return __uint_as_float(((unsigned)u)<<16); }
__device__ __forceinline__ void gload16(const ushort_t* g, ushort_t* l){
  __builtin_amdgcn_global_load_lds((const __attribute__((address_space(1))) void*)g,
                                   (__attribute__((address_space(3))) void*)l,16,0,0);
}

__device__ __forceinline__ void ast32(void* p, unsigned v){
  __hip_atomic_store((unsigned*)p,v,__ATOMIC_RELAXED,__HIP_MEMORY_SCOPE_AGENT);
}
__device__ __forceinline__ void ast64(void* p, ull_t v){
  __hip_atomic_store((ull_t*)p,v,__ATOMIC_RELAXED,__HIP_MEMORY_SCOPE_AGENT);
}

__device__ __forceinline__ void arrive(unsigned* flags, int idx, unsigned ep){
  if(threadIdx.x==0) ast32(&flags[idx*16], ep);
}
__device__ __forceinline__ void wait_flags(unsigned* flags, int n, unsigned ep){
  for(int i=threadIdx.x;i<n;i+=256){
    while(__hip_atomic_load(&flags[i*16],__ATOMIC_RELAXED,__HIP_MEMORY_SCOPE_AGENT)<ep)
      __builtin_amdgcn_s_sleep(1);
  }
  __syncthreads();
}

// ---- staging: 128 rows x 64 cols via global_load_lds, XOR-swizzled granules ----
__device__ __forceinline__ void stage128(const ushort_t* src, int ld, int k0,
                                         ushort_t* lds, int w, int lane){
  const int rA=lane>>3, gA=lane&7;
#pragma unroll
  for(int i=0;i<4;i++){
    int rb=w*32+i*8;
    int row=rb+rA;
    gload16(src+(size_t)row*ld+k0+(((gA)^(row&7))*8), &lds[rb*64]);
  }
}
// ---- staging: 256 rows x 64 cols with 1024 threads; LDS base WAVE-UNIFORM ----
__device__ __forceinline__ void stage256(const ushort_t* src, int ld, int k0,
                                         ushort_t* lds, int w, int lane){
#pragma unroll
  for(int p=0;p<2;p++){
    int s0=p*1024+w*64;          // wave-uniform LDS base element
    int s=s0+lane;
    int row=s>>3, g=s&7;
    gload16(src+(size_t)row*ld+k0+((g^(row&7))*8), &lds[(size_t)s0*8]);
  }
}

// ---- named-accumulator MFMA machinery ----
#define ACC_DECL \
  f32x4 c00={0,0,0,0},c01={0,0,0,0},c02={0,0,0,0},c03={0,0,0,0}, \
        c10={0,0,0,0},c11={0,0,0,0},c12={0,0,0,0},c13={0,0,0,0}, \
        c20={0,0,0,0},c21={0,0,0,0},c22={0,0,0,0},c23={0,0,0,0}, \
        c30={0,0,0,0},c31={0,0,0,0},c32={0,0,0,0},c33={0,0,0,0};

#define MFMA_ __builtin_amdgcn_mfma_f32_16x16x32_bf16
#define MMA_K64(AsB,BsB) do{ \
  _Pragma("unroll") \
  for(int ks_=0;ks_<2;ks_++){ \
    const int sw_=((ks_*4+l4)^l7)*8; \
    bf16x8 a0_=*(const bf16x8*)&(AsB)[(wm*64+ 0+l15)*64+sw_]; \
    bf16x8 a1_=*(const bf16x8*)&(AsB)[(wm*64+16+l15)*64+sw_]; \
    bf16x8 a2_=*(const bf16x8*)&(AsB)[(wm*64+32+l15)*64+sw_]; \
    bf16x8 a3_=*(const bf16x8*)&(AsB)[(wm*64+48+l15)*64+sw_]; \
    bf16x8 b0_=*(const bf16x8*)&(BsB)[(wn*64+ 0+l15)*64+sw_]; \
    bf16x8 b1_=*(const bf16x8*)&(BsB)[(wn*64+16+l15)*64+sw_]; \
    bf16x8 b2_=*(const bf16x8*)&(BsB)[(wn*64+32+l15)*64+sw_]; \
    bf16x8 b3_=*(const bf16x8*)&(BsB)[(wn*64+48+l15)*64+sw_]; \
    c00=MFMA_(a0_,b0_,c00,0,0,0); c01=MFMA_(a0_,b1_,c01,0,0,0); \
    c02=MFMA_(a0_,b2_,c02,0,0,0); c03=MFMA_(a0_,b3_,c03,0,0,0); \
    c10=MFMA_(a1_,b0_,c10,0,0,0); c11=MFMA_(a1_,b1_,c11,0,0,0); \
    c12=MFMA_(a1_,b2_,c12,0,0,0); c13=MFMA_(a1_,b3_,c13,0,0,0); \
    c20=MFMA_(a2_,b0_,c20,0,0,0); c21=MFMA_(a2_,b1_,c21,0,0,0); \
    c22=MFMA_(a2_,b2_,c22,0,0,0); c23=MFMA_(a2_,b3_,c23,0,0,0); \
    c30=MFMA_(a3_,b0_,c30,0,0,0); c31=MFMA_(a3_,b1_,c31,0,0,0); \
    c32=MFMA_(a3_,b2_,c32,0,0,0); c33=MFMA_(a3_,b3_,c33,0,0,0); \
  } \
}while(0)

// ---- proj3: z=0 xprojF, z=1 xprojB, z=2 yproj. BF16 out + optional bias ----
__global__ __launch_bounds__(256)
void proj3(const ushort_t* __restrict__ Xb, const ushort_t* __restrict__ WfB, const float* __restrict__ bf,
           const ushort_t* __restrict__ XrB, const ushort_t* __restrict__ WbB, const float* __restrict__ bb,
           const ushort_t* __restrict__ Yb, const ushort_t* __restrict__ WyB,
           ushort_t* __restrict__ XpF, ushort_t* __restrict__ XpB, ushort_t* __restrict__ Yp)
{
  __shared__ __align__(16) ushort_t As[128*64];
  __shared__ __align__(16) ushort_t Bs[128*64];
  const ushort_t* A; const ushort_t* B; const float* bias; ushort_t* C;
  if(blockIdx.z==0){A=Xb;B=WfB;bias=bf;C=XpF;}
  else if(blockIdx.z==1){A=XrB;B=WbB;bias=bb;C=XpB;}
  else {A=Yb;B=WyB;bias=nullptr;C=Yp;}
  const int tid=threadIdx.x, w=tid>>6, lane=tid&63;
  const int wm=w>>1, wn=w&1;
  const int l15=lane&15, l4=lane>>4, l7=lane&7;
  const int m0=blockIdx.x*128, n0=blockIdx.y*128;
  ACC_DECL
  for(int k0=0;k0<E_;k0+=64){
    stage128(A+(size_t)m0*E_, E_, k0, As, w, lane);
    stage128(B+(size_t)n0*E_, E_, k0, Bs, w, lane);
    __syncthreads();
    MMA_K64(As,Bs);
    __syncthreads();
  }
  const int cr=l4*4, cc=l15;
#define PSTORE(CM,mi,ni) { int col=n0+wn*64+(ni)*16+cc; float bv=bias?bias[col]:0.f; \
  _Pragma("unroll") for(int j=0;j<4;j++){ int row=m0+wm*64+(mi)*16+cr+j; \
    C[(size_t)row*H4_+col]=f2bs(CM[j]+bv); } }
  PSTORE(c00,0,0) PSTORE(c01,0,1) PSTORE(c02,0,2) PSTORE(c03,0,3)
  PSTORE(c10,1,0) PSTORE(c11,1,1) PSTORE(c12,1,2) PSTORE(c13,1,3)
  PSTORE(c20,2,0) PSTORE(c21,2,1) PSTORE(c22,2,2) PSTORE(c23,2,3)
  PSTORE(c30,3,0) PSTORE(c31,3,1) PSTORE(c32,3,2) PSTORE(c33,3,3)
#undef PSTORE
}

// ---- bproj: bf16-out NT GEMM (encP and G) ----
__global__ __launch_bounds__(256)
void bproj(const ushort_t* __restrict__ A, int lda,
           const ushort_t* __restrict__ B, int ldb, int K,
           ushort_t* __restrict__ Cb)
{
  __shared__ __align__(16) ushort_t As[128*64];
  __shared__ __align__(16) ushort_t Bs[128*64];
  const int tid=threadIdx.x, w=tid>>6, lane=tid&63;
  const int wm=w>>1, wn=w&1;
  const int l15=lane&15, l4=lane>>4, l7=lane&7;
  const int m0=blockIdx.x*128, n0=blockIdx.y*128;
  ACC_DECL
  for(int k0=0;k0<K;k0+=64){
    stage128(A+(size_t)m0*lda, lda, k0, As, w, lane);
    stage128(B+(size_t)n0*ldb, ldb, k0, Bs, w, lane);
    __syncthreads();
    MMA_K64(As,Bs);
    __syncthreads();
  }
  const int cr=l4*4, cc=l15;
#define BSTORE(CM,mi,ni) { int col=n0+wn*64+(ni)*16+cc; \
  _Pragma("unroll") for(int j=0;j<4;j++){ int row=m0+wm*64+(mi)*16+cr+j; \
    Cb[(size_t)row*H_+col]=f2bs(CM[j]); } }
  BSTORE(c00,0,0) BSTORE(c01,0,1) BSTORE(c02,0,2) BSTORE(c03,0,3)
  BSTORE(c10,1,0) BSTORE(c11,1,1) BSTORE(c12,1,2) BSTORE(c13,1,3)
  BSTORE(c20,2,0) BSTORE(c21,2,1) BSTORE(c22,2,2) BSTORE(c23,2,3)
  BSTORE(c30,3,0) BSTORE(c31,3,1) BSTORE(c32,3,2) BSTORE(c33,3,3)
#undef BSTORE
}

// ---- vocab GEMM 256x256 (1024 thr, 4x4 waves) + fused LSE partials + gold ----
__global__ __launch_bounds__(1024)
void mfma_vocab(const ushort_t* __restrict__ A, const ushort_t* __restrict__ B,
                const int* __restrict__ tgt,
                float* __restrict__ pmax, float* __restrict__ psum, float* __restrict__ gold)
{
  __shared__ __align__(16) ushort_t As[256*64];
  __shared__ __align__(16) ushort_t Bs[256*64];
  const int tid=threadIdx.x, w=tid>>6, lane=tid&63;
  const int wm=w>>2, wn=w&3;
  const int l15=lane&15, l4=lane>>4, l7=lane&7;
  const int m0=blockIdx.x*256, n0=blockIdx.y*256;
  ACC_DECL
  for(int k0=0;k0<H_;k0+=64){
    stage256(A+(size_t)m0*H_, H_, k0, As, w, lane);
    stage256(B+(size_t)n0*H_, H_, k0, Bs, w, lane);
    __syncthreads();
    MMA_K64(As,Bs);
    __syncthreads();
  }
  const int tile=blockIdx.y*4+wn;
  const int cc=l15;
#define VEPI(mi,R0,R1,R2,R3) { \
  _Pragma("unroll") for(int j=0;j<4;j++){ \
    int row=m0+wm*64+(mi)*16+l4*4+j; \
    float m=fmaxf(fmaxf(R0[j],R1[j]),fmaxf(R2[j],R3[j])); \
    for(int o=1;o<16;o<<=1) m=fmaxf(m,__shfl_xor(m,o,64)); \
    float s=expf(R0[j]-m)+expf(R1[j]-m)+expf(R2[j]-m)+expf(R3[j]-m); \
    for(int o=1;o<16;o<<=1) s+=__shfl_xor(s,o,64); \
    if(row<NROW_){ \
      if(cc==0){ pmax[(size_t)tile*NROWP+row]=m; psum[(size_t)tile*NROWP+row]=s; } \
      int g=tgt[((row>>6)+1)*B_+(row&63)]; \
      int lj=g-(n0+wn*64); \
      if(lj>=0&&lj<64&&(lj&15)==cc){ int q=lj>>4; \
        gold[row]= (q==0)?R0[j]:(q==1)?R1[j]:(q==2)?R2[j]:R3[j]; } \
    } } }
  VEPI(0,c00,c01,c02,c03)
  VEPI(1,c10,c11,c12,c13)
  VEPI(2,c20,c21,c22,c23)
  VEPI(3,c30,c31,c32,c33)
#undef VEPI
}

// ====== persistent encoder: rotating h slots; bf16 xp; sc1 writes, normal reads =====
__global__ __launch_bounds__(256)
void enc_persist(const ushort_t* __restrict__ WhhB2,
                 const ushort_t* __restrict__ XpF, const ushort_t* __restrict__ XpB,
                 const int* __restrict__ lens,
                 ushort_t* __restrict__ hroll,
                 float* __restrict__ cst,
                 ushort_t* __restrict__ outF, ushort_t* __restrict__ outBR,
                 unsigned* __restrict__ flagsE)
{
  __shared__ __align__(16) ushort_t Bp[64*1024];
  const int tid=threadIdx.x, w=tid>>6, lane=tid&63;
  const int blk=blockIdx.x, dir=blk>>6, j0=(blk&63)*16;
  const int l15=lane&15, l4=lane>>4;
  const ushort_t* Wd=WhhB2+(size_t)dir*H4_*H_;
  const ushort_t* xp = dir? XpB : XpF;
  float* cD = cst + (size_t)dir*65536;
  ushort_t* outD = dir? outBR : outF;
  unsigned* fD = flagsE + dir*64*16;

  for(int p=0;p<32;p++){
    int s=p*256+w*64+lane;
    int row=s>>7, g=s&127;
    int grow=((row>>4)<<10)+j0+(row&15);
    gload16(Wd+(size_t)grow*H_+((g^(row&7))*8), &Bp[(p*256+w*64)*8]);
  }
  __syncthreads();

  float hkeep[4]={0.f,0.f,0.f,0.f};

  for(int t=0;t<S_;t++){
    const ushort_t* hbR = hroll + ((size_t)t*2+dir)*65536;
    ushort_t*       hbW = hroll + ((size_t)(t+1)*2+dir)*65536;
    bf16x8 a[32];
    {
      const ushort_t* ap=hbR+(size_t)(w*16+l15)*H_+l4*8;
#pragma unroll
      for(int kk=0;kk<32;kk++) a[kk]=*(const bf16x8*)(ap+kk*32);
    }
    f32x4 acc[4];
#pragma unroll
    for(int n=0;n<4;n++) acc[n]=(f32x4){0.f,0.f,0.f,0.f};
#pragma unroll
    for(int kk=0;kk<32;kk++){
#pragma unroll
      for(int n=0;n<4;n++){
        int rb=n*16+l15;
        bf16x8 b=*(const bf16x8*)&Bp[rb*H_+(((kk*4+l4)^(rb&7))*8)];
        acc[n]=__builtin_amdgcn_mfma_f32_16x16x32_bf16(a[kk],b,acc[n],0,0,0);
      }
    }
    const int col=j0+l15;
#pragma unroll
    for(int j=0;j<4;j++){
      int row=w*16+l4*4+j;
      const ushort_t* xr=xp+(size_t)(t*64+row)*H4_;
      float g0=acc[0][j]+b2f(xr[col]);
      float g1=acc[1][j]+b2f(xr[1024+col]);
      float g2=acc[2][j]+b2f(xr[2048+col]);
      float g3=acc[3][j]+b2f(xr[3072+col]);
      size_t ix=(size_t)row*H_+col;
      float c_old=cD[ix];
      float cn=sigm(g1)*c_old+sigm(g0)*tanhf(g2);
      float hv=sigm(g3)*tanhf(cn);
      bool m=t<lens[row];
      cD[ix]= m? cn : c_old;
      hkeep[j]= m? hv : hkeep[j];
      outD[(size_t)(t*64+row)*H_+col]= m? f2bs(hv) : (ushort_t)0;
      ushort_t h16=f2bs(hkeep[j]);
      ushort_t other=(ushort_t)__shfl_xor((int)h16,1,64);
      if((lane&1)==0)
        ast32((void*)(hbW+ix), (unsigned)h16 | ((unsigned)other<<16));
    }
    __syncthreads();
    arrive(fD, blk&63, (unsigned)(t+1));
    wait_flags(fD, 64, (unsigned)(t+1));
  }
}

// ====== persistent decoder: 2 sync rounds/step (fp32 accRoll) =======================
__global__ __launch_bounds__(256)
void dec_persist(const ushort_t* __restrict__ WoB,
                 const ushort_t* __restrict__ Yp,
                 const float* __restrict__ whhC,
                 const float* __restrict__ dc0,
                 const ushort_t* __restrict__ encPb,
                 const ushort_t* __restrict__ Gb,
                 const ushort_t* __restrict__ WcombB,
                 const int* __restrict__ lens,
                 ushort_t* __restrict__ opRoll,
                 ushort_t* __restrict__ hRoll,
                 float* __restrict__ accRoll,      // [T1_][64][1024] fp32 (raw accP)
                 ushort_t* __restrict__ combB,
                 unsigned* __restrict__ fA,
                 unsigned* __restrict__ fB,
                 unsigned* __restrict__ fM)
{
  __shared__ __align__(16) ushort_t Bp[32*1024];
  __shared__ __align__(16) ushort_t WcHp[16*1024];
  __shared__ float gbuf[64*32];
  __shared__ float whhCs[64*32];
  __shared__ float dc0s[64*8];
  __shared__ float es[S_], al[S_];
  const int tid=threadIdx.x, w=tid>>6, lane=tid&63;
  const int blk=blockIdx.x;
  const int l15=lane&15, l4=lane>>4;
  const int j0=blk*8;
  const int b=blk;
  const int j0c=(blk-64)*16;

  for(int p=0;p<16;p++){
    int s=p*256+w*64+lane;
    int row=s>>7, g=s&127;
    int grow=((row>>3)<<10)+j0+(row&7);
    gload16(WoB+(size_t)grow*H_+((g^(row&7))*8), &Bp[(p*256+w*64)*8]);
  }
  if(blk>=64){
    for(int p=0;p<8;p++){
      int s=p*256+w*64+lane;
      int row=s>>7, g=s&127;
      gload16(WcombB+(size_t)(j0c+row)*3072+2048+((g^(row&7))*8), &WcHp[(p*256+w*64)*8]);
    }
  }
  for(int p=0;p<8;p++){
    int s=p*256+tid;
    int row=s>>5, gc=s&31, gate=gc>>3, c=gc&7;
    whhCs[s]=whhC[(size_t)row*H4_+gate*1024+j0+c];
  }
  if(tid<512){ int row=tid>>3, c=tid&7; dc0s[tid]=dc0[(size_t)row*H_+j0+c]; }
  __syncthreads();

  for(int t=0;t<T1_;t++){
    const unsigned ept=(unsigned)(t+1);
    const ushort_t* opT = opRoll + (size_t)t*65536;
    ushort_t*       opW = opRoll + (size_t)(t+1)*65536;
    ushort_t*       hT  = hRoll  + (size_t)t*65536;
    float*          accT= accRoll+ (size_t)t*65536;
    // ---------------- PA ----------------
    {
      bf16x8 a[32];
      {
        const ushort_t* ap=opT+(size_t)(w*16+l15)*H_+l4*8;
#pragma unroll
        for(int kk=0;kk<32;kk++) a[kk]=*(const bf16x8*)(ap+kk*32);
      }
      f32x4 acc0=(f32x4){0.f,0.f,0.f,0.f}, acc1=(f32x4){0.f,0.f,0.f,0.f};
#pragma unroll
      for(int kk=0;kk<32;kk++){
        int rb0=l15, rb1=16+l15;
        bf16x8 b0=*(const bf16x8*)&Bp[rb0*1024+(((kk*4+l4)^(rb0&7))*8)];
        bf16x8 b1=*(const bf16x8*)&Bp[rb1*1024+(((kk*4+l4)^(rb1&7))*8)];
        acc0=__builtin_amdgcn_mfma_f32_16x16x32_bf16(a[kk],b0,acc0,0,0,0);
        acc1=__builtin_amdgcn_mfma_f32_16x16x32_bf16(a[kk],b1,acc1,0,0,0);
      }
#pragma unroll
      for(int j=0;j<4;j++){
        gbuf[(w*16+l4*4+j)*32 + l15   ]=acc0[j];
        gbuf[(w*16+l4*4+j)*32 + 16+l15]=acc1[j];
      }
      __syncthreads();
      {
        int o=tid*2, row=o>>3, c=o&7;
        const ushort_t* ypr=Yp+(size_t)(t*64+row)*H4_;
        float hv2[2];
#pragma unroll
        for(int q=0;q<2;q++){
          int cc=c+q;
          float g0=gbuf[row*32+cc]   +b2f(ypr[j0+cc])     +whhCs[row*32+cc];
          float g1=gbuf[row*32+8+cc] +b2f(ypr[1024+j0+cc])+whhCs[row*32+8+cc];
          float g2=gbuf[row*32+16+cc]+b2f(ypr[2048+j0+cc])+whhCs[row*32+16+cc];
          float g3=gbuf[row*32+24+cc]+b2f(ypr[3072+j0+cc])+whhCs[row*32+24+cc];
          float cn=sigm(g1)*dc0s[row*8+cc]+sigm(g0)*tanhf(g2);
          hv2[q]=sigm(g3)*tanhf(cn);
        }
        unsigned pk=(unsigned)f2bs(hv2[0]) | ((unsigned)f2bs(hv2[1])<<16);
        ast32((void*)(hT+(size_t)row*H_+j0+c), pk);
      }
    }
    __syncthreads();
    arrive(fA, blk, ept);
    wait_flags(fA, 128, ept);

    if(blk<64){
      // ------------- PB: attention, aG stays in registers -----------------
      float hreg[16];
      {
        const ushort_t* hp=hT+(size_t)b*H_+lane*16;
        bf16x8 h0=*(const bf16x8*)hp, h1=*(const bf16x8*)(hp+8);
#pragma unroll
        for(int i=0;i<8;i++){ hreg[i]=b2f(((const ushort_t*)&h0)[i]);
                              hreg[8+i]=b2f(((const ushort_t*)&h1)[i]); }
      }
      for(int s=w;s<S_;s+=4){
        const ushort_t* epr=encPb+((size_t)b*S_+s)*H_+lane*16;
        bf16x8 e0=*(const bf16x8*)epr, e1=*(const bf16x8*)(epr+8);
        float sum=0.f;
#pragma unroll
        for(int i=0;i<8;i++) sum+=b2f(((const ushort_t*)&e0)[i])*hreg[i]
                                +b2f(((const ushort_t*)&e1)[i])*hreg[8+i];
        for(int o=32;o>0;o>>=1) sum+=__shfl_xor(sum,o,64);
        if(lane==0) es[s]=sum;
      }
      __syncthreads();
      if(tid<64){
        int L=lens[b];
        float e=(tid<S_&&tid<L)? es[tid] : -INFINITY;
        float m=e;
        for(int o=32;o>0;o>>=1) m=fmaxf(m,__shfl_xor(m,o,64));
        float p=(tid<S_)? expf(e-m):0.f;
        float sm=p;
        for(int o=32;o>0;o>>=1) sm+=__shfl_xor(sm,o,64);
        if(tid<S_) al[tid]=p/sm;
      }
      __syncthreads();
      float r0=0.f,r1=0.f,r2=0.f,r3=0.f;
      const int c4=tid*4;
      for(int s=0;s<S_;s++){
        float aa=al[s];
        ushort4 g4=*(const ushort4*)(Gb+((size_t)b*S_+s)*H_+c4);
        r0+=aa*b2f(g4.x); r1+=aa*b2f(g4.y); r2+=aa*b2f(g4.z); r3+=aa*b2f(g4.w);
      }
      // wait for raw accP (PCmm signals early; usually already satisfied)
      wait_flags(fM, 64, ept);
      {
        float4 ap4=*(const float4*)(accT+(size_t)b*H_+c4);
        float o0=tanhf(r0+ap4.x);
        float o1=tanhf(r1+ap4.y);
        float o2=tanhf(r2+ap4.z);
        float o3=tanhf(r3+ap4.w);
        ushort_t b0=f2bs(o0),b1=f2bs(o1),b2_=f2bs(o2),b3=f2bs(o3);
        ull_t pk=(ull_t)b0 | ((ull_t)b1<<16) | ((ull_t)b2_<<32) | ((ull_t)b3<<48);
        ast64((void*)(opW+(size_t)b*H_+c4), pk);
        ushort4 cb; cb.x=b0; cb.y=b1; cb.z=b2_; cb.w=b3;
        *(ushort4*)(combB+((size_t)t*64+b)*H_+c4)=cb;
      }
      __syncthreads();
      arrive(fB, blk, ept);
      wait_flags(fB, 64, ept);
    } else {
      // ------------- PCmm: raw accP = h @ WcH^T -> accRoll (fp32), signal fM ----
      bf16x8 a[32];
      {
        const ushort_t* ap=hT+(size_t)(w*16+l15)*H_+l4*8;
#pragma unroll
        for(int kk=0;kk<32;kk++) a[kk]=*(const bf16x8*)(ap+kk*32);
      }
      f32x4 accP=(f32x4){0.f,0.f,0.f,0.f};
#pragma unroll
      for(int kk=0;kk<32;kk++){
        bf16x8 bb=*(const bf16x8*)&WcHp[l15*1024+(((kk*4+l4)^(l15&7))*8)];
        accP=__builtin_amdgcn_mfma_f32_16x16x32_bf16(a[kk],bb,accP,0,0,0);
      }
#pragma unroll
      for(int j=0;j<4;j++){
        int row=w*16+l4*4+j, col=j0c+l15;
        float v=accP[j];
        float other=__shfl_xor(v,1,64);
        if((lane&1)==0){
          union{ float f[2]; ull_t q; } u; u.f[0]=v; u.f[1]=other;
          ast64((void*)(accT+(size_t)row*H_+col), u.q);
        }
      }
      __syncthreads();
      arrive(fM, blk-64, ept);
      wait_flags(fB, 64, ept);
    }
  }
}

// ------------------ embeddings (direct to bf16): X, Xrev, Y -------------------------
__global__ void embed_all(const int* __restrict__ src, const int* __restrict__ tgt,
                          const int* __restrict__ lens,
                          const float* __restrict__ se, const float* __restrict__ te,
                          ushort_t* __restrict__ X, ushort_t* __restrict__ Xr,
                          ushort_t* __restrict__ Y)
{
  int bi=blockIdx.x, tid=threadIdx.x;
  const float* srcrow; ushort_t* dst;
  if(bi<3072){
    int s=bi>>6, b=bi&63;
    srcrow=se+(size_t)src[s*64+b]*E_; dst=X+(size_t)bi*E_;
  } else if(bi<6144){
    int r=bi-3072, t=r>>6, b=r&63;
    int L=lens[b]; int ts=(t<L)? L-1-t : t;
    srcrow=se+(size_t)src[ts*64+b]*E_; dst=Xr+(size_t)r*E_;
  } else {
    int r=bi-6144, t=r>>6, b=r&63;
    srcrow=te+(size_t)tgt[t*64+b]*E_; dst=Y+(size_t)r*E_;
  }
  float4 v=((const float4*)srcrow)[tid];
  ushort4 o; o.x=f2bs(v.x); o.y=f2bs(v.y); o.z=f2bs(v.z); o.w=f2bs(v.w);
  ((ushort4*)dst)[tid]=o;
}

// ------------- weight conversions fp32->bf16 (all but W_voc), grid-stride -----------
__global__ void prep_w(const float* __restrict__ Whhf,const float* __restrict__ Whhb,
                       const float* __restrict__ Wihf,const float* __restrict__ Wihb,
                       const float* __restrict__ Watt,const float* __restrict__ dWih,
                       const float* __restrict__ Wcomb,
                       ushort_t* __restrict__ WhhfB,ushort_t* __restrict__ WhhbB,
                       ushort_t* __restrict__ WihfB,ushort_t* __restrict__ WihbB,
                       ushort_t* __restrict__ WattB,ushort_t* __restrict__ dWihYb,
                       ushort_t* __restrict__ dWihOb,ushort_t* __restrict__ WcombB)
{
  const int NQ=6029312;
  for(int q=blockIdx.x*256+threadIdx.x; q<NQ; q+=gridDim.x*256){
    const float* src; ushort_t* dst; size_t si,di; int r;
    if(q<1048576){ si=(size_t)q*4; src=Whhf; dst=WhhfB; di=si; }
    else if(q<2097152){ r=q-1048576; si=(size_t)r*4; src=Whhb; dst=WhhbB; di=si; }
    else if(q<2621440){ r=q-2097152; si=(size_t)r*4; src=Wihf; dst=WihfB; di=si; }
    else if(q<3145728){ r=q-2621440; si=(size_t)r*4; src=Wihb; dst=WihbB; di=si; }
    else if(q<3670016){ r=q-3145728; si=(size_t)r*4; src=Watt; dst=WattB; di=si; }
    else if(q<4194304){ r=q-3670016; int row=r>>7, c4=(r&127)*4;
                        si=(size_t)row*1536+c4; src=dWih; dst=dWihYb; di=(size_t)row*512+c4; }
    else if(q<5242880){ r=q-4194304; int row=r>>8, c4=(r&255)*4;
                        si=(size_t)row*1536+512+c4; src=dWih; dst=dWihOb; di=(size_t)row*1024+c4; }
    else { r=q-5242880; si=(size_t)r*4; src=Wcomb; dst=WcombB; di=si; }
    float4 v=*(const float4*)(src+si);
    ushort4 o; o.x=f2bs(v.x);o.y=f2bs(v.y);o.z=f2bs(v.z);o.w=f2bs(v.w);
    *(ushort4*)(dst+di)=o;
  }
}

__global__ void f2b_voc(const float* __restrict__ in, ushort_t* __restrict__ out){
  for(size_t q=blockIdx.x*256+threadIdx.x; q<8192000; q+=(size_t)gridDim.x*256){
    float4 v=*(const float4*)(in+q*4);
    ushort4 o; o.x=f2bs(v.x);o.y=f2bs(v.y);o.z=f2bs(v.z);o.w=f2bs(v.w);
    *(ushort4*)(out+q*4)=o;
  }
}

// --- build enc_hiddens bf16 with bwd un-reversal; concat final h/c (fp32) -----------
__global__ void gather_concat(const ushort_t* __restrict__ outF, const ushort_t* __restrict__ outBR,
                              const int* __restrict__ lens,
                              const ushort_t* __restrict__ hb, const float* __restrict__ cst,
                              ushort_t* __restrict__ encHb,
                              float* __restrict__ hcat, float* __restrict__ ccat)
{
  int bi=blockIdx.x, tid=threadIdx.x;
  if(bi<3072){
    int b=bi/48, s=bi%48;
    int L=lens[b]; int sr=(s<L)? L-1-s : s;
    ((ushort4*)(encHb+(size_t)bi*2048))[tid]      =((const ushort4*)(outF +(size_t)(s*64+b)*H_))[tid];
    ((ushort4*)(encHb+(size_t)bi*2048+1024))[tid] =((const ushort4*)(outBR+(size_t)(sr*64+b)*H_))[tid];
  } else {
    int b=bi-3072;
    for(int i=tid;i<H_;i+=256){
      hcat[(size_t)b*2048+i]      = b2f(hb[(size_t)b*H_+i]);
      hcat[(size_t)b*2048+1024+i] = b2f(hb[65536+(size_t)b*H_+i]);
      ccat[(size_t)b*2048+i]      = cst[(size_t)b*H_+i];
      ccat[(size_t)b*2048+1024+i] = cst[65536+(size_t)b*H_+i];
    }
  }
}

// ---------------- fp32 NT GEMM (small: dh0/dc0/whhC) --------------------------------
template<int BM,int BN,int TM,int TN>
__global__ __launch_bounds__(256)
void gemm_nt(int M, int K,
             const float* __restrict__ A, int lda,
             const float* __restrict__ B, int ldb,
             float* __restrict__ C, int ldc,
             const float* __restrict__ bias)
{
  constexpr int BK=16;
  __shared__ float As[BK][BM+4];
  __shared__ float Bs[BK][BN+4];
  const int tid=threadIdx.x;
  constexpr int TX=BN/TN;
  const int tx=tid%TX, ty=tid/TX;
  const int m0=blockIdx.x*BM, n0=blockIdx.y*BN;
  float acc[TM][TN];
#pragma unroll
  for(int i=0;i<TM;i++)
#pragma unroll
    for(int j=0;j<TN;j++) acc[i][j]=0.f;
  for(int k0=0;k0<K;k0+=BK){
    for(int i=tid;i<BM*4;i+=256){
      int r=i>>2, c=(i&3)*4;
      float4 v=make_float4(0.f,0.f,0.f,0.f);
      if(m0+r<M) v=*(const float4*)(A+(size_t)(m0+r)*lda+k0+c);
      As[c+0][r]=v.x; As[c+1][r]=v.y; As[c+2][r]=v.z; As[c+3][r]=v.w;
    }
    for(int i=tid;i<BN*4;i+=256){
      int r=i>>2, c=(i&3)*4;
      float4 v=*(const float4*)(B+(size_t)(n0+r)*ldb+k0+c);
      Bs[c+0][r]=v.x; Bs[c+1][r]=v.y; Bs[c+2][r]=v.z; Bs[c+3][r]=v.w;
    }
    __syncthreads();
#pragma unroll
    for(int k=0;k<BK;k++){
      float a[TM], bb[TN];
#pragma unroll
      for(int i=0;i<TM;i++) a[i]=As[k][ty*TM+i];
#pragma unroll
      for(int j=0;j<TN;j++) bb[j]=Bs[k][tx*TN+j];
#pragma unroll
      for(int i=0;i<TM;i++)
#pragma unroll
        for(int j=0;j<TN;j++) acc[i][j]+=a[i]*bb[j];
    }
    __syncthreads();
  }
#pragma unroll
  for(int i=0;i<TM;i++){
    int r=m0+ty*TM+i;
    if(r>=M) continue;
#pragma unroll
    for(int j=0;j<TN;j++){
      int c=n0+tx*TN+j;
      float v=acc[i][j];
      if(bias) v+=bias[c];
      C[(size_t)r*ldc+c]=v;
    }
  }
}

// ---- streaming LSE merge over tile-major partials (coalesced, single pass) ---------
__global__ __launch_bounds__(256)
void lse_final(const float* __restrict__ pmax, const float* __restrict__ psum,
               const float* __restrict__ gold, float* __restrict__ gl)
{
  int r=blockIdx.x*256+threadIdx.x;
  if(r>=NROW_) return;
  float M=-INFINITY, S=0.f;
  for(int i=0;i<NTV_;i++){
    float m2=pmax[(size_t)i*NROWP+r];
    float s2=psum[(size_t)i*NROWP+r];
    float Mn=fmaxf(M,m2);
    S = S*expf(M-Mn) + s2*expf(m2-Mn);
    M=Mn;
  }
  gl[r]=gold[r]-(M+logf(S));
}

__global__ void final_sum(const float* __restrict__ gl, const int* __restrict__ tgt,
                          float* __restrict__ out)
{
  int b=threadIdx.x;
  float acc=0.f;
  for(int t=0;t<T1_;t++){
    int tk=tgt[(t+1)*B_+b];
    if(tk!=0) acc+=gl[t*B_+b];
  }
  out[b]=acc;
}

// =====================================================================================
extern "C" void kernel_launch(void* const* d_in, const int* in_sizes, int n_in,
                              void* d_out, int out_size, void* d_ws, size_t ws_size,
                              hipStream_t stream)
{
  (void)in_sizes; (void)n_in; (void)out_size; (void)ws_size;
  const int*   src    =(const int*)  d_in[0];
  const int*   tgt    =(const int*)  d_in[1];
  const int*   lens   =(const int*)  d_in[2];
  const float* src_emb=(const float*)d_in[3];
  const float* tgt_emb=(const float*)d_in[4];
  const float* Wih_f  =(const float*)d_in[5];
  const float* Whh_f  =(const float*)d_in[6];
  const float* b_f    =(const float*)d_in[7];
  const float* Wih_b  =(const float*)d_in[8];
  const float* Whh_b  =(const float*)d_in[9];
  const float* b_b    =(const float*)d_in[10];
  const float* dWih   =(const float*)d_in[11];
  const float* dWhh   =(const float*)d_in[12];
  const float* db     =(const float*)d_in[13];
  const float* W_h    =(const float*)d_in[14];
  const float* W_c    =(const float*)d_in[15];
  const float* W_att  =(const float*)d_in[16];
  const float* W_comb =(const float*)d_in[17];
  const float* W_voc  =(const float*)d_in[18];
  float* out=(float*)d_out;
  float* W  =(float*)d_ws;

  size_t off=0;
  auto AL=[&](size_t n){ size_t o=off; off+=n; return o; };
  // ---- fp32 region ----
  const size_t oXpF  =AL((size_t)3072*H4_);
  const size_t oXpB  =AL((size_t)3072*H4_);
  const size_t oYp   =AL((size_t)3072*H4_);   // bf16 Yp uses floats [0,6.29M);
                                              // fp32 accRoll uses [6.30M,9.39M)
  const size_t oCst  =AL((size_t)2*64*H_);
  const size_t oHcat =AL((size_t)64*2048);
  const size_t oCcat =AL((size_t)64*2048);
  const size_t oDh0  =AL((size_t)64*H_);
  const size_t oDc0  =AL((size_t)64*H_);
  const size_t oWhhC =AL((size_t)64*H4_);
  const size_t oBar  =AL((size_t)8192);
  // ---- bf16 region ----
  const size_t oXb    =AL((size_t)3072*E_/2);
  const size_t oXrb   =AL((size_t)3072*E_/2);
  const size_t oYb    =AL((size_t)3072*E_/2);
  const size_t oWhhfB =AL((size_t)H4_*H_/2);
  const size_t oWhhbB =AL((size_t)H4_*H_/2);
  const size_t oWihfB =AL((size_t)H4_*E_/2);
  const size_t oWihbB =AL((size_t)H4_*E_/2);
  const size_t oWattB =AL((size_t)H_*2048/2);
  const size_t odWihYb=AL((size_t)H4_*E_/2);
  const size_t odWihOb=AL((size_t)H4_*H_/2);
  const size_t oWcombB=AL((size_t)H_*3072/2);
  const size_t oOutF  =AL((size_t)S_*64*H_/2);
  const size_t oOutBR =AL((size_t)S_*64*H_/2);
  const size_t oEncHb =AL((size_t)3072*2048/2);
  const size_t oEncPb =AL((size_t)3072*H_/2);

  ushort_t* Xb    =(ushort_t*)(W+oXb);
  ushort_t* Xrb   =(ushort_t*)(W+oXrb);
  ushort_t* Yb    =(ushort_t*)(W+oYb);
  ushort_t* WhhfB =(ushort_t*)(W+oWhhfB);
  ushort_t* WihfB =(ushort_t*)(W+oWihfB);
  ushort_t* WihbB =(ushort_t*)(W+oWihbB);
  ushort_t* WattB =(ushort_t*)(W+oWattB);
  ushort_t* dWihYb=(ushort_t*)(W+odWihYb);
  ushort_t* dWihOb=(ushort_t*)(W+odWihOb);
  ushort_t* WcombB=(ushort_t*)(W+oWcombB);
  ushort_t* OutF  =(ushort_t*)(W+oOutF);
  ushort_t* OutBR =(ushort_t*)(W+oOutBR);
  ushort_t* EncHb =(ushort_t*)(W+oEncHb);
  ushort_t* EncPb =(ushort_t*)(W+oEncPb);
  ushort_t* XpFb  =(ushort_t*)(W+oXpF);
  ushort_t* XpBb  =(ushort_t*)(W+oXpB);
  ushort_t* YpB   =(ushort_t*)(W+oYp);
  float*    AccRoll = W+oYp+6300000;             // fp32, 47 x 65536 floats
  // ---- aliases in dead XpF+XpB region (post-encoder only) ----
  ushort_t* WvocB =(ushort_t*)(W+oXpF);
  float* pmax = W+oXpF+16450000;
  float* psum = pmax + (size_t)NTV_*NROWP;
  ushort_t* Gbuf  =(ushort_t*)(W+oXpF+19550000);
  ushort_t* OpRoll=(ushort_t*)(W+oXpF+21150000);
  ushort_t* HRoll =(ushort_t*)(W+oXpF+22750000);
  float* gold = W+oXpF+24400000;
  float* gl   = gold + NROWP;
  ushort_t* HrollE=EncHb;
  ushort_t* HbFin =HrollE+(size_t)S_*2*65536;
  ushort_t* CombB =(ushort_t*)(W+oOutF);
  unsigned* flagsE=(unsigned*)(W+oBar);
  unsigned* fA = flagsE + 2*64*16;
  unsigned* fB = fA + 128*16;
  unsigned* fM = fB + 64*16;

  // ---- per-call init ----
  hipMemsetAsync(W+oBar, 0, 8192*sizeof(float), stream);
  hipMemsetAsync(W+oCst, 0, (size_t)2*64*H_*sizeof(float), stream);
  hipMemsetAsync(HrollE, 0, (size_t)2*65536*sizeof(ushort_t), stream);

  // ---- prep ----
  embed_all<<<dim3(3072+3072+NROW_),128,0,stream>>>(src,tgt,lens,src_emb,tgt_emb,Xb,Xrb,Yb);
  prep_w<<<dim3(2048),256,0,stream>>>(Whh_f,Whh_b,Wih_f,Wih_b,W_att,dWih,W_comb,
                                      WhhfB,(ushort_t*)(W+oWhhbB),WihfB,WihbB,WattB,
                                      dWihYb,dWihOb,WcombB);
  proj3<<<dim3(24,32,3),256,0,stream>>>(Xb,WihfB,b_f, Xrb,WihbB,b_b, Yb,dWihYb,
                                        XpFb,XpBb,YpB);

  // ---- encoder ----
  enc_persist<<<dim3(NBE),256,0,stream>>>(WhhfB, XpFb, XpBb, lens,
                                          HrollE, W+oCst, OutF, OutBR, flagsE);

  // OpRoll slot 0 sits in the (now dead) XpB region -> zero after encoder.
  hipMemsetAsync(OpRoll, 0, (size_t)65536*sizeof(ushort_t), stream);

  // ---- mid section ----
  gather_concat<<<dim3(3136),256,0,stream>>>(OutF,OutBR,lens,HbFin,W+oCst,
                                             EncHb,W+oHcat,W+oCcat);
  f2b_voc<<<dim3(2048),256,0,stream>>>(W_voc, WvocB);
  bproj<<<dim3(24,8),256,0,stream>>>(EncHb,2048, WattB,2048, 2048, EncPb);
  bproj<<<dim3(24,8),256,0,stream>>>(EncHb,2048, WcombB,3072, 2048, Gbuf);
  gemm_nt<64,64,4,4><<<dim3(1,16),256,0,stream>>>(64,2048, W+oHcat,2048, W_h,2048, W+oDh0,H_, nullptr);
  gemm_nt<64,64,4,4><<<dim3(1,16),256,0,stream>>>(64,2048, W+oCcat,2048, W_c,2048, W+oDc0,H_, nullptr);
  gemm_nt<64,64,4,4><<<dim3(1,64),256,0,stream>>>(64,H_, W+oDh0,H_, dWhh,H_, W+oWhhC,H4_, db);

  // ---- decoder (2 sync rounds/step, fp32 accRoll) ----
  dec_persist<<<dim3(NBD),256,0,stream>>>(dWihOb, YpB, W+oWhhC, W+oDc0,
                                          EncPb, Gbuf, WcombB, lens,
                                          OpRoll, HRoll, AccRoll, CombB, fA, fB, fM);

  // ---- vocab (256x256, uniform-base staging) + LSE + output ----
  mfma_vocab<<<dim3(12,125),1024,0,stream>>>(CombB, WvocB, tgt, pmax, psum, gold);
  lse_final<<<dim3((NROW_+255)/256),256,0,stream>>>(pmax, psum, gold, gl);
  final_sum<<<dim3(1),64,0,stream>>>(gl, tgt, out);
}